// Round 1
// baseline (943.657 us; speedup 1.0000x reference)
//
#include <hip/hip_runtime.h>
#include <math.h>

// Problem constants
#define PS    64          // patch size
#define WSZ   11          // SSIM gaussian window
#define RAD   5           // WSZ/2
#define C1C   1e-4f       // 0.01^2
#define C2C   9e-4f       // 0.03^2
// Layout: inputs (32, 3, 512, 512) fp32. 8x8 patches of 64x64 per image.
// plane id = (patch q)*3 + channel c ; q = b*64 + ph*8 + pw

// ---------------------------------------------------------------------------
// Kernel 1: per patch-channel plane, compute sum of SSIM map (separable conv)
// grid = (2048, 3), block = 256. LDS = 64 KiB (X, Y, S1, S2).
// ---------------------------------------------------------------------------
__global__ __launch_bounds__(256) void ssim_plane_kernel(
    const float* __restrict__ Nimg, const float* __restrict__ GTimg,
    float* __restrict__ ssim_sum)
{
    __shared__ float X[64][64];
    __shared__ float Y[64][64];
    __shared__ float S1[64][64];
    __shared__ float S2[64][64];

    const int q  = blockIdx.x;           // 0..2047 patch
    const int c  = blockIdx.y;           // 0..2 channel
    const int b  = q >> 6;
    const int pp = q & 63;
    const int ph = pp >> 3;
    const int pw = pp & 7;
    const size_t base = ((size_t)(b * 3 + c) << 18)   // *512*512
                      + ((size_t)(ph * 64) << 9)      // *512
                      + (size_t)(pw * 64);

    const int t = threadIdx.x;

    // Gaussian weights (exact match of reference: exp(-(k-5)^2/4.5), normalized)
    float g[WSZ];
    {
        float s = 0.f;
        #pragma unroll
        for (int k = 0; k < WSZ; ++k) {
            float d = (float)(k - RAD);
            g[k] = expf(-d * d / 4.5f);
            s += g[k];
        }
        float inv = 1.f / s;
        #pragma unroll
        for (int k = 0; k < WSZ; ++k) g[k] *= inv;
    }

    // Load 64x64 planes (float4, coalesced: 16 consecutive lanes cover one row)
    #pragma unroll
    for (int it = 0; it < 4; ++it) {
        int idx  = t + 256 * it;          // 0..1023
        int row  = idx >> 4;
        int col4 = (idx & 15) << 2;
        size_t off = base + ((size_t)row << 9) + col4;
        float4 xv = *(const float4*)(Nimg + off);
        float4 yv = *(const float4*)(GTimg + off);
        *(float4*)&X[row][col4] = xv;
        *(float4*)&Y[row][col4] = yv;
    }
    __syncthreads();

    const int j  = t & 63;     // column (lane -> consecutive cols, conflict-free)
    const int ib = t >> 6;     // base row (0..3); rows i = ib + 4*r

    float mu1[16], mu2[16], vxx[16], vyy[16];

    // ---- Pass 1: horizontal x, y -> S1, S2 ----
    #pragma unroll 4
    for (int r = 0; r < 16; ++r) {
        int i = ib + (r << 2);
        float hx = 0.f, hy = 0.f;
        #pragma unroll
        for (int k = 0; k < WSZ; ++k) {
            int jj = j + k - RAD;
            if (jj >= 0 && jj < 64) {
                hx += g[k] * X[i][jj];
                hy += g[k] * Y[i][jj];
            }
        }
        S1[i][j] = hx;
        S2[i][j] = hy;
    }
    __syncthreads();

    // ---- Pass 1 vertical: mu1, mu2 ----
    #pragma unroll 4
    for (int r = 0; r < 16; ++r) {
        int i = ib + (r << 2);
        float m1 = 0.f, m2 = 0.f;
        #pragma unroll
        for (int k = 0; k < WSZ; ++k) {
            int ii = i + k - RAD;
            if (ii >= 0 && ii < 64) {
                m1 += g[k] * S1[ii][j];
                m2 += g[k] * S2[ii][j];
            }
        }
        mu1[r] = m1;
        mu2[r] = m2;
    }
    __syncthreads();

    // ---- Pass 2: horizontal x*x, y*y -> S1, S2 ----
    #pragma unroll 4
    for (int r = 0; r < 16; ++r) {
        int i = ib + (r << 2);
        float hxx = 0.f, hyy = 0.f;
        #pragma unroll
        for (int k = 0; k < WSZ; ++k) {
            int jj = j + k - RAD;
            if (jj >= 0 && jj < 64) {
                float xv = X[i][jj];
                float yv = Y[i][jj];
                hxx += g[k] * xv * xv;
                hyy += g[k] * yv * yv;
            }
        }
        S1[i][j] = hxx;
        S2[i][j] = hyy;
    }
    __syncthreads();

    // ---- Pass 2 vertical: E[x^2], E[y^2] ----
    #pragma unroll 4
    for (int r = 0; r < 16; ++r) {
        int i = ib + (r << 2);
        float sxx = 0.f, syy = 0.f;
        #pragma unroll
        for (int k = 0; k < WSZ; ++k) {
            int ii = i + k - RAD;
            if (ii >= 0 && ii < 64) {
                sxx += g[k] * S1[ii][j];
                syy += g[k] * S2[ii][j];
            }
        }
        vxx[r] = sxx;
        vyy[r] = syy;
    }
    __syncthreads();

    // ---- Pass 3: horizontal x*y -> S1 ----
    #pragma unroll 4
    for (int r = 0; r < 16; ++r) {
        int i = ib + (r << 2);
        float hxy = 0.f;
        #pragma unroll
        for (int k = 0; k < WSZ; ++k) {
            int jj = j + k - RAD;
            if (jj >= 0 && jj < 64) {
                hxy += g[k] * X[i][jj] * Y[i][jj];
            }
        }
        S1[i][j] = hxy;
    }
    __syncthreads();

    // ---- Pass 3 vertical: E[xy]; combine into SSIM map, accumulate ----
    float acc = 0.f;
    #pragma unroll 4
    for (int r = 0; r < 16; ++r) {
        int i = ib + (r << 2);
        float sxy = 0.f;
        #pragma unroll
        for (int k = 0; k < WSZ; ++k) {
            int ii = i + k - RAD;
            if (ii >= 0 && ii < 64) {
                sxy += g[k] * S1[ii][j];
            }
        }
        float m1  = mu1[r], m2 = mu2[r];
        float m1s = m1 * m1, m2s = m2 * m2, m12 = m1 * m2;
        float s1  = vxx[r] - m1s;
        float s2v = vyy[r] - m2s;
        float s12 = sxy    - m12;
        float num = (2.f * m12 + C1C) * (2.f * s12 + C2C);
        float den = (m1s + m2s + C1C) * (s1 + s2v + C2C);
        acc += num / den;
    }

    // ---- block reduction (wave shfl, then LDS partials reusing S2) ----
    #pragma unroll
    for (int off = 32; off; off >>= 1)
        acc += __shfl_down(acc, off, 64);
    __syncthreads();                  // S1/S2 no longer needed; reuse S2 row 0
    if ((t & 63) == 0) S2[0][t >> 6] = acc;
    __syncthreads();
    if (t == 0) {
        float ssum = S2[0][0] + S2[0][1] + S2[0][2] + S2[0][3];
        ssim_sum[q * 3 + c] = ssum;   // every plane written -> no ws zeroing
    }
}

// ---------------------------------------------------------------------------
// Kernel 2: per patch MSE losses + combine with SSIM, atomicAdd to out.
// grid = 2048, block = 256.
// ---------------------------------------------------------------------------
__global__ __launch_bounds__(256) void loss_kernel(
    const float* __restrict__ A, const float* __restrict__ G,
    const float* __restrict__ BG, const float* __restrict__ ssim_sum,
    float* __restrict__ out)
{
    const int q  = blockIdx.x;
    const int b  = q >> 6;
    const int pp = q & 63;
    const int ph = pp >> 3;
    const int pw = pp & 7;
    const size_t imgBase = ((size_t)(b * 3) << 18)
                         + ((size_t)(ph * 64) << 9)
                         + (size_t)(pw * 64);

    const int t = threadIdx.x;
    float sbg = 0.f, sa = 0.f;

    // 3 channels * 64 rows * 16 float4 = 3072 float4 per patch, 12 per thread
    #pragma unroll 4
    for (int r = 0; r < 12; ++r) {
        int idx4 = t + 256 * r;            // 0..3071
        int c    = idx4 >> 10;             // 1024 float4 per channel
        int rem  = idx4 & 1023;
        int y    = rem >> 4;
        int x4   = (rem & 15) << 2;
        size_t off = imgBase + ((size_t)c << 18) + ((size_t)y << 9) + x4;
        float4 av  = *(const float4*)(A  + off);
        float4 gv  = *(const float4*)(G  + off);
        float4 bgv = *(const float4*)(BG + off);
        float d0 = bgv.x - gv.x, d1 = bgv.y - gv.y, d2 = bgv.z - gv.z, d3 = bgv.w - gv.w;
        sbg += d0 * d0 + d1 * d1 + d2 * d2 + d3 * d3;
        float e0 = av.x - gv.x, e1 = av.y - gv.y, e2 = av.z - gv.z, e3 = av.w - gv.w;
        sa  += e0 * e0 + e1 * e1 + e2 * e2 + e3 * e3;
    }

    // block reduction
    __shared__ float redbg[4];
    __shared__ float reda[4];
    #pragma unroll
    for (int off = 32; off; off >>= 1) {
        sbg += __shfl_down(sbg, off, 64);
        sa  += __shfl_down(sa,  off, 64);
    }
    if ((t & 63) == 0) { redbg[t >> 6] = sbg; reda[t >> 6] = sa; }
    __syncthreads();
    if (t == 0) {
        float sbgT = redbg[0] + redbg[1] + redbg[2] + redbg[3];
        float saT  = reda[0]  + reda[1]  + reda[2]  + reda[3];
        float ssum = ssim_sum[q * 3 + 0] + ssim_sum[q * 3 + 1] + ssim_sum[q * 3 + 2];
        const float invN = 1.f / 12288.f;      // 3*64*64
        float ssim    = ssum * invN;
        float diff    = fminf(1.f - ssim, 1.f);   // LD = 1.0
        float bg_loss = sbgT * invN;
        float a_loss  = saT  * invN;
        float loss = diff * bg_loss + (1.f - diff) * a_loss;
        atomicAdd(out, loss);
    }
}

extern "C" void kernel_launch(void* const* d_in, const int* in_sizes, int n_in,
                              void* d_out, int out_size, void* d_ws, size_t ws_size,
                              hipStream_t stream) {
    const float* A  = (const float*)d_in[0];
    const float* Nn = (const float*)d_in[1];
    const float* GT = (const float*)d_in[2];
    const float* G  = (const float*)d_in[3];
    const float* BG = (const float*)d_in[4];
    float* out      = (float*)d_out;
    float* ssim_sum = (float*)d_ws;          // 6144 floats

    // out is poisoned 0xAA before every timed launch -> zero it (capturable)
    hipMemsetAsync(d_out, 0, sizeof(float), stream);

    ssim_plane_kernel<<<dim3(2048, 3), 256, 0, stream>>>(Nn, GT, ssim_sum);
    loss_kernel<<<2048, 256, 0, stream>>>(A, G, BG, ssim_sum, out);
}

// Round 2
// 487.180 us; speedup vs baseline: 1.9370x; 1.9370x over previous
//
#include <hip/hip_runtime.h>
#include <math.h>

// Constants
#define WSZ 11
#define RAD 5
#define C1C 1e-4f       // 0.01^2
#define C2C 9e-4f       // 0.03^2
// Inputs: (32, 3, 512, 512) fp32; 8x8 patches of 64x64. plane = q*3 + c.
// S-buffer row stride 68 floats: keeps 16B alignment for b128 and spreads
// banks so the 16-rows-per-wave b128 read/write pattern is conflict-free.

// ---------------------------------------------------------------------------
// Fused kernel: per (patch q, channel c) plane:
//   - separable 11x11 gaussian convs (register-blocked, 2 rounds, 3 LDS bufs)
//   - SSIM map sum
//   - MSE partial sums for (BG-G)^2 and (A-G)^2
// grid (2048, 3), block 256. LDS = 3*64*68*4 = 52224 B -> 3 blocks/CU.
// ---------------------------------------------------------------------------
__global__ __launch_bounds__(256, 3) void ssim_fused_kernel(
    const float* __restrict__ A,  const float* __restrict__ Nimg,
    const float* __restrict__ GT, const float* __restrict__ G,
    const float* __restrict__ BG,
    float* __restrict__ ssim_sum, float* __restrict__ sa_sum,
    float* __restrict__ sbg_sum)
{
    __shared__ float S0[64][68];
    __shared__ float S1[64][68];
    __shared__ float S2[64][68];

    const int q  = blockIdx.x;          // patch 0..2047
    const int c  = blockIdx.y;          // channel 0..2
    const int b  = q >> 6;
    const int pp = q & 63;
    const int ph = pp >> 3;
    const int pw = pp & 7;
    const size_t base = ((size_t)(b * 3 + c) << 18)
                      + ((size_t)(ph * 64) << 9)
                      + (size_t)(pw * 64);
    const int t = threadIdx.x;

    // Gaussian weights (matches reference: exp(-(k-5)^2/4.5), normalized)
    float g[WSZ];
    {
        float s = 0.f;
        #pragma unroll
        for (int k = 0; k < WSZ; ++k) {
            float d = (float)(k - RAD);
            g[k] = expf(-d * d / 4.5f);
            s += g[k];
        }
        float inv = 1.f / s;
        #pragma unroll
        for (int k = 0; k < WSZ; ++k) g[k] *= inv;
    }

    // Horizontal mapping: thread -> (row hr, 16-col segment hc)
    const int hr = t >> 2;
    const int hc = (t & 3) << 4;
    const size_t rowBase = base + ((size_t)hr << 9);

    // ---------------- Round 1 horizontal: hx, hy, hxy ----------------
    {
        float xw[32], yw[32];
        #pragma unroll
        for (int m = 0; m < 8; ++m) {
            const int cb = hc - 8 + 4 * m;
            float4 xv = make_float4(0.f, 0.f, 0.f, 0.f);
            float4 yv = make_float4(0.f, 0.f, 0.f, 0.f);
            if (cb >= 0 && cb < 64) {           // zero padding outside patch
                xv = *(const float4*)(Nimg + rowBase + cb);
                yv = *(const float4*)(GT   + rowBase + cb);
            }
            xw[4*m+0] = xv.x; xw[4*m+1] = xv.y; xw[4*m+2] = xv.z; xw[4*m+3] = xv.w;
            yw[4*m+0] = yv.x; yw[4*m+1] = yv.y; yw[4*m+2] = yv.z; yw[4*m+3] = yv.w;
        }
        float pxy[32];
        #pragma unroll
        for (int i = 0; i < 32; ++i) pxy[i] = xw[i] * yw[i];

        #pragma unroll
        for (int m = 0; m < 4; ++m) {
            float4 o0, o1, o2;
            #pragma unroll
            for (int u = 0; u < 4; ++u) {
                const int o = 4 * m + u;
                float hx = 0.f, hy = 0.f, hxy = 0.f;
                #pragma unroll
                for (int k = 0; k < WSZ; ++k) {
                    const float gw = g[k];
                    hx  = fmaf(gw, xw[o + 3 + k], hx);
                    hy  = fmaf(gw, yw[o + 3 + k], hy);
                    hxy = fmaf(gw, pxy[o + 3 + k], hxy);
                }
                (&o0.x)[u] = hx; (&o1.x)[u] = hy; (&o2.x)[u] = hxy;
            }
            *(float4*)&S0[hr][hc + 4*m] = o0;
            *(float4*)&S1[hr][hc + 4*m] = o1;
            *(float4*)&S2[hr][hc + 4*m] = o2;
        }
    }
    __syncthreads();

    // Vertical mapping: thread -> (col vj, 16-row stripe vr0)
    const int vj  = t & 63;
    const int vr0 = (t >> 6) << 4;

    float mu1[16], mu2[16], Exy[16];
    // ---------------- Round 1 vertical ----------------
    {
        float w[26];
        #pragma unroll
        for (int d = 0; d < 26; ++d) {
            const int row = vr0 - 5 + d;
            w[d] = (row >= 0 && row < 64) ? S0[row][vj] : 0.f;
        }
        #pragma unroll
        for (int o = 0; o < 16; ++o) {
            float acc = 0.f;
            #pragma unroll
            for (int k = 0; k < WSZ; ++k) acc = fmaf(g[k], w[o + k], acc);
            mu1[o] = acc;
        }
    }
    {
        float w[26];
        #pragma unroll
        for (int d = 0; d < 26; ++d) {
            const int row = vr0 - 5 + d;
            w[d] = (row >= 0 && row < 64) ? S1[row][vj] : 0.f;
        }
        #pragma unroll
        for (int o = 0; o < 16; ++o) {
            float acc = 0.f;
            #pragma unroll
            for (int k = 0; k < WSZ; ++k) acc = fmaf(g[k], w[o + k], acc);
            mu2[o] = acc;
        }
    }
    {
        float w[26];
        #pragma unroll
        for (int d = 0; d < 26; ++d) {
            const int row = vr0 - 5 + d;
            w[d] = (row >= 0 && row < 64) ? S2[row][vj] : 0.f;
        }
        #pragma unroll
        for (int o = 0; o < 16; ++o) {
            float acc = 0.f;
            #pragma unroll
            for (int k = 0; k < WSZ; ++k) acc = fmaf(g[k], w[o + k], acc);
            Exy[o] = acc;
        }
    }
    __syncthreads();

    // ---------------- Round 2 horizontal: hxx, hyy ----------------
    {
        float xw[32], yw[32];
        #pragma unroll
        for (int m = 0; m < 8; ++m) {
            const int cb = hc - 8 + 4 * m;
            float4 xv = make_float4(0.f, 0.f, 0.f, 0.f);
            float4 yv = make_float4(0.f, 0.f, 0.f, 0.f);
            if (cb >= 0 && cb < 64) {           // L1/L2-resident re-read
                xv = *(const float4*)(Nimg + rowBase + cb);
                yv = *(const float4*)(GT   + rowBase + cb);
            }
            xw[4*m+0] = xv.x; xw[4*m+1] = xv.y; xw[4*m+2] = xv.z; xw[4*m+3] = xv.w;
            yw[4*m+0] = yv.x; yw[4*m+1] = yv.y; yw[4*m+2] = yv.z; yw[4*m+3] = yv.w;
        }
        #pragma unroll
        for (int i = 0; i < 32; ++i) { xw[i] *= xw[i]; yw[i] *= yw[i]; }

        #pragma unroll
        for (int m = 0; m < 4; ++m) {
            float4 o0, o1;
            #pragma unroll
            for (int u = 0; u < 4; ++u) {
                const int o = 4 * m + u;
                float hxx = 0.f, hyy = 0.f;
                #pragma unroll
                for (int k = 0; k < WSZ; ++k) {
                    const float gw = g[k];
                    hxx = fmaf(gw, xw[o + 3 + k], hxx);
                    hyy = fmaf(gw, yw[o + 3 + k], hyy);
                }
                (&o0.x)[u] = hxx; (&o1.x)[u] = hyy;
            }
            *(float4*)&S0[hr][hc + 4*m] = o0;
            *(float4*)&S1[hr][hc + 4*m] = o1;
        }
    }
    __syncthreads();

    // ---------------- Round 2 vertical + SSIM combine ----------------
    float Exx[16];
    {
        float w[26];
        #pragma unroll
        for (int d = 0; d < 26; ++d) {
            const int row = vr0 - 5 + d;
            w[d] = (row >= 0 && row < 64) ? S0[row][vj] : 0.f;
        }
        #pragma unroll
        for (int o = 0; o < 16; ++o) {
            float acc = 0.f;
            #pragma unroll
            for (int k = 0; k < WSZ; ++k) acc = fmaf(g[k], w[o + k], acc);
            Exx[o] = acc;
        }
    }
    float accS = 0.f;
    {
        float w[26];
        #pragma unroll
        for (int d = 0; d < 26; ++d) {
            const int row = vr0 - 5 + d;
            w[d] = (row >= 0 && row < 64) ? S1[row][vj] : 0.f;
        }
        #pragma unroll
        for (int o = 0; o < 16; ++o) {
            float Eyy = 0.f;
            #pragma unroll
            for (int k = 0; k < WSZ; ++k) Eyy = fmaf(g[k], w[o + k], Eyy);
            const float m1 = mu1[o], m2 = mu2[o];
            const float m1s = m1 * m1, m2s = m2 * m2, m12 = m1 * m2;
            const float s1  = Exx[o] - m1s;
            const float s2v = Eyy    - m2s;
            const float s12 = Exy[o] - m12;
            const float num = (2.f * m12 + C1C) * (2.f * s12 + C2C);
            const float den = (m1s + m2s + C1C) * (s1 + s2v + C2C);
            accS += num / den;
        }
    }

    // ---------------- Fused MSE partials over this plane ----------------
    float sa = 0.f, sbg = 0.f;
    #pragma unroll
    for (int it = 0; it < 4; ++it) {
        const int idx  = t + 256 * it;        // 0..1023 float4 slots
        const int row  = idx >> 4;
        const int col4 = (idx & 15) << 2;
        const size_t off = base + ((size_t)row << 9) + col4;
        const float4 av  = *(const float4*)(A  + off);
        const float4 gv  = *(const float4*)(G  + off);
        const float4 bgv = *(const float4*)(BG + off);
        float d0 = bgv.x - gv.x, d1 = bgv.y - gv.y, d2 = bgv.z - gv.z, d3 = bgv.w - gv.w;
        sbg += d0*d0 + d1*d1 + d2*d2 + d3*d3;
        float e0 = av.x - gv.x, e1 = av.y - gv.y, e2 = av.z - gv.z, e3 = av.w - gv.w;
        sa  += e0*e0 + e1*e1 + e2*e2 + e3*e3;
    }

    // ---------------- Block reduction of (accS, sa, sbg) ----------------
    #pragma unroll
    for (int off = 32; off; off >>= 1) {
        accS += __shfl_down(accS, off, 64);
        sa   += __shfl_down(sa,   off, 64);
        sbg  += __shfl_down(sbg,  off, 64);
    }
    __syncthreads();                      // S reads all done; reuse S0 area
    if ((t & 63) == 0) {
        const int w = t >> 6;
        S0[0][w] = accS; S0[1][w] = sa; S0[2][w] = sbg;
    }
    __syncthreads();
    if (t == 0) {
        const int plane = q * 3 + c;
        ssim_sum[plane] = S0[0][0] + S0[0][1] + S0[0][2] + S0[0][3];
        sa_sum[plane]   = S0[1][0] + S0[1][1] + S0[1][2] + S0[1][3];
        sbg_sum[plane]  = S0[2][0] + S0[2][1] + S0[2][2] + S0[2][3];
    }
}

// ---------------------------------------------------------------------------
// Final combine: 1 block, 256 threads, no atomics, deterministic.
// ---------------------------------------------------------------------------
__global__ __launch_bounds__(256) void combine_kernel(
    const float* __restrict__ ssim_sum, const float* __restrict__ sa_sum,
    const float* __restrict__ sbg_sum, float* __restrict__ out)
{
    __shared__ float red[4];
    const int t = threadIdx.x;
    const float invN = 1.f / 12288.f;     // 3*64*64
    float acc = 0.f;
    #pragma unroll
    for (int r = 0; r < 8; ++r) {
        const int qq = t + 256 * r;       // patch 0..2047
        const float ss = ssim_sum[3*qq] + ssim_sum[3*qq+1] + ssim_sum[3*qq+2];
        const float sa = sa_sum[3*qq]   + sa_sum[3*qq+1]   + sa_sum[3*qq+2];
        const float sb = sbg_sum[3*qq]  + sbg_sum[3*qq+1]  + sbg_sum[3*qq+2];
        const float ssim = ss * invN;
        const float diff = fminf(1.f - ssim, 1.f);     // LD = 1.0
        acc += diff * (sb * invN) + (1.f - diff) * (sa * invN);
    }
    #pragma unroll
    for (int off = 32; off; off >>= 1) acc += __shfl_down(acc, off, 64);
    if ((t & 63) == 0) red[t >> 6] = acc;
    __syncthreads();
    if (t == 0) out[0] = red[0] + red[1] + red[2] + red[3];
}

extern "C" void kernel_launch(void* const* d_in, const int* in_sizes, int n_in,
                              void* d_out, int out_size, void* d_ws, size_t ws_size,
                              hipStream_t stream) {
    const float* A  = (const float*)d_in[0];
    const float* Nn = (const float*)d_in[1];
    const float* GT = (const float*)d_in[2];
    const float* G  = (const float*)d_in[3];
    const float* BG = (const float*)d_in[4];
    float* out      = (float*)d_out;

    float* ssim_sum = (float*)d_ws;            // 6144 floats
    float* sa_sum   = ssim_sum + 6144;         // 6144 floats
    float* sbg_sum  = ssim_sum + 12288;        // 6144 floats

    ssim_fused_kernel<<<dim3(2048, 3), 256, 0, stream>>>(
        A, Nn, GT, G, BG, ssim_sum, sa_sum, sbg_sum);
    combine_kernel<<<1, 256, 0, stream>>>(ssim_sum, sa_sum, sbg_sum, out);
}

// Round 3
// 431.869 us; speedup vs baseline: 2.1851x; 1.1281x over previous
//
#include <hip/hip_runtime.h>
#include <math.h>

#define C1C 1e-4f       // 0.01^2
#define C2C 9e-4f       // 0.03^2
// Inputs: (32, 3, 512, 512) fp32; 8x8 patches of 64x64. plane = q*3 + c.
// LDS buffers stride 68 floats: 16B-aligned rows for b128, vertical reads
// conflict-free (lanes = consecutive cols).

// Gaussian weights g[k] = exp(-(k-5)^2/4.5)/sum, precomputed in fp64.
#define GW0 0.00102838f
#define GW1 0.00759876f
#define GW2 0.03600077f
#define GW3 0.10936069f
#define GW4 0.21300554f
#define GW5 0.26601173f
__device__ __forceinline__ float conv11(const float* w) {
    // w points at first tap of an 11-wide window
    float a = GW0 * (w[0] + w[10]);
    a = fmaf(GW1, w[1] + w[9], a);
    a = fmaf(GW2, w[2] + w[8], a);
    a = fmaf(GW3, w[3] + w[7], a);
    a = fmaf(GW4, w[4] + w[6], a);
    a = fmaf(GW5, w[5], a);
    return a;
}

// Load a 26-row column window from S (rows vr0-5 .. vr0+20) into w[26].
// wid = t>>6 is wave-uniform -> branches don't diverge within a wave.
__device__ __forceinline__ void load_col26(const float (*S)[68], int col,
                                           int wid, float* w) {
    if (wid == 0) {
        #pragma unroll
        for (int d = 0; d < 5; ++d) w[d] = 0.f;
        #pragma unroll
        for (int d = 5; d < 26; ++d) w[d] = S[d - 5][col];
    } else if (wid == 3) {
        #pragma unroll
        for (int d = 0; d < 21; ++d) w[d] = S[43 + d][col];
        #pragma unroll
        for (int d = 21; d < 26; ++d) w[d] = 0.f;
    } else {
        const int base = (wid << 4) - 5;
        #pragma unroll
        for (int d = 0; d < 26; ++d) w[d] = S[base + d][col];
    }
}

// ---------------------------------------------------------------------------
// Fused: per (patch q, channel c) plane: separable 11x11 gaussian convs
// (register-blocked, single global read of N/GT), SSIM-map sum, MSE partials.
// grid (2048, 3), block 256. LDS = 3*64*68*4 = 52224 B -> 3 blocks/CU.
// ---------------------------------------------------------------------------
__global__ __launch_bounds__(256, 3) void ssim_fused_kernel(
    const float* __restrict__ A,  const float* __restrict__ Nimg,
    const float* __restrict__ GT, const float* __restrict__ G,
    const float* __restrict__ BG,
    float* __restrict__ ssim_sum, float* __restrict__ sa_sum,
    float* __restrict__ sbg_sum)
{
    __shared__ float S0[64][68];
    __shared__ float S1[64][68];
    __shared__ float S2[64][68];

    const int q  = blockIdx.x;          // patch 0..2047
    const int c  = blockIdx.y;          // channel 0..2
    const int b  = q >> 6;
    const int pp = q & 63;
    const int ph = pp >> 3;
    const int pw = pp & 7;
    const size_t base = ((size_t)(b * 3 + c) << 18)
                      + ((size_t)(ph * 64) << 9)
                      + (size_t)(pw * 64);
    const int t = threadIdx.x;

    // Horizontal mapping: thread -> (row hr, 16-col segment hc)
    const int hr = t >> 2;
    const int hc = (t & 3) << 4;
    const size_t rowBase = base + ((size_t)hr << 9);

    float hxx[16], hyy[16];

    // ---------------- Horizontal: hx, hy, hxy -> LDS; hxx, hyy -> regs ------
    {
        float xw[32], yw[32];
        #pragma unroll
        for (int m = 0; m < 8; ++m) {
            const int cb = hc - 8 + 4 * m;
            float4 xv = make_float4(0.f, 0.f, 0.f, 0.f);
            float4 yv = make_float4(0.f, 0.f, 0.f, 0.f);
            if (cb >= 0 && cb < 64) {           // zero padding outside patch
                xv = *(const float4*)(Nimg + rowBase + cb);
                yv = *(const float4*)(GT   + rowBase + cb);
            }
            xw[4*m+0] = xv.x; xw[4*m+1] = xv.y; xw[4*m+2] = xv.z; xw[4*m+3] = xv.w;
            yw[4*m+0] = yv.x; yw[4*m+1] = yv.y; yw[4*m+2] = yv.z; yw[4*m+3] = yv.w;
        }

        float tp[32];                           // x*y products
        #pragma unroll
        for (int i = 0; i < 32; ++i) tp[i] = xw[i] * yw[i];
        #pragma unroll
        for (int m = 0; m < 4; ++m) {
            float4 o0, o1, o2;
            #pragma unroll
            for (int u = 0; u < 4; ++u) {
                const int o = 4 * m + u;
                (&o0.x)[u] = conv11(&xw[o + 3]);
                (&o1.x)[u] = conv11(&yw[o + 3]);
                (&o2.x)[u] = conv11(&tp[o + 3]);
            }
            *(float4*)&S0[hr][hc + 4*m] = o0;
            *(float4*)&S1[hr][hc + 4*m] = o1;
            *(float4*)&S2[hr][hc + 4*m] = o2;
        }
        #pragma unroll
        for (int i = 0; i < 32; ++i) tp[i] = xw[i] * xw[i];   // x^2
        #pragma unroll
        for (int o = 0; o < 16; ++o) hxx[o] = conv11(&tp[o + 3]);
        #pragma unroll
        for (int i = 0; i < 32; ++i) tp[i] = yw[i] * yw[i];   // y^2
        #pragma unroll
        for (int o = 0; o < 16; ++o) hyy[o] = conv11(&tp[o + 3]);
    }
    __syncthreads();

    // Vertical mapping: thread -> (col vj, 16-row stripe wid*16)
    const int vj  = t & 63;
    const int wid = t >> 6;

    float mu1[16], mu2[16], Exy[16];
    {
        float w[26];
        load_col26(S0, vj, wid, w);
        #pragma unroll
        for (int o = 0; o < 16; ++o) mu1[o] = conv11(&w[o]);
        load_col26(S1, vj, wid, w);
        #pragma unroll
        for (int o = 0; o < 16; ++o) mu2[o] = conv11(&w[o]);
        load_col26(S2, vj, wid, w);
        #pragma unroll
        for (int o = 0; o < 16; ++o) Exy[o] = conv11(&w[o]);
    }
    __syncthreads();

    // ---------------- Write hxx, hyy (kept in regs) to S0, S1 --------------
    #pragma unroll
    for (int m = 0; m < 4; ++m) {
        float4 o0, o1;
        #pragma unroll
        for (int u = 0; u < 4; ++u) {
            (&o0.x)[u] = hxx[4*m + u];
            (&o1.x)[u] = hyy[4*m + u];
        }
        *(float4*)&S0[hr][hc + 4*m] = o0;
        *(float4*)&S1[hr][hc + 4*m] = o1;
    }
    __syncthreads();

    // ---------------- Vertical round 2 + SSIM combine ----------------------
    float accS = 0.f;
    {
        float Exx[16];
        float w[26];
        load_col26(S0, vj, wid, w);
        #pragma unroll
        for (int o = 0; o < 16; ++o) Exx[o] = conv11(&w[o]);
        load_col26(S1, vj, wid, w);
        #pragma unroll
        for (int o = 0; o < 16; ++o) {
            const float Eyy = conv11(&w[o]);
            const float m1 = mu1[o], m2 = mu2[o];
            const float m1s = m1 * m1, m2s = m2 * m2, m12 = m1 * m2;
            const float s1  = Exx[o] - m1s;
            const float s2v = Eyy    - m2s;
            const float s12 = Exy[o] - m12;
            const float num = (2.f * m12 + C1C) * (2.f * s12 + C2C);
            const float den = (m1s + m2s + C1C) * (s1 + s2v + C2C);
            accS += num / den;
        }
    }

    // ---------------- Fused MSE partials over this plane -------------------
    float sa = 0.f, sbg = 0.f;
    #pragma unroll
    for (int it = 0; it < 4; ++it) {
        const int idx  = t + 256 * it;        // 0..1023 float4 slots
        const int row  = idx >> 4;
        const int col4 = (idx & 15) << 2;
        const size_t off = base + ((size_t)row << 9) + col4;
        const float4 av  = *(const float4*)(A  + off);
        const float4 gv  = *(const float4*)(G  + off);
        const float4 bgv = *(const float4*)(BG + off);
        float d0 = bgv.x - gv.x, d1 = bgv.y - gv.y, d2 = bgv.z - gv.z, d3 = bgv.w - gv.w;
        sbg += d0*d0 + d1*d1 + d2*d2 + d3*d3;
        float e0 = av.x - gv.x, e1 = av.y - gv.y, e2 = av.z - gv.z, e3 = av.w - gv.w;
        sa  += e0*e0 + e1*e1 + e2*e2 + e3*e3;
    }

    // ---------------- Block reduction of (accS, sa, sbg) -------------------
    #pragma unroll
    for (int off = 32; off; off >>= 1) {
        accS += __shfl_down(accS, off, 64);
        sa   += __shfl_down(sa,   off, 64);
        sbg  += __shfl_down(sbg,  off, 64);
    }
    __syncthreads();                      // all S reads done; reuse S0 area
    if ((t & 63) == 0) {
        S0[0][wid] = accS; S0[1][wid] = sa; S0[2][wid] = sbg;
    }
    __syncthreads();
    if (t == 0) {
        const int plane = q * 3 + c;
        ssim_sum[plane] = S0[0][0] + S0[0][1] + S0[0][2] + S0[0][3];
        sa_sum[plane]   = S0[1][0] + S0[1][1] + S0[1][2] + S0[1][3];
        sbg_sum[plane]  = S0[2][0] + S0[2][1] + S0[2][2] + S0[2][3];
    }
}

// ---------------------------------------------------------------------------
// Final combine: 1 block, 256 threads, no atomics, deterministic.
// ---------------------------------------------------------------------------
__global__ __launch_bounds__(256) void combine_kernel(
    const float* __restrict__ ssim_sum, const float* __restrict__ sa_sum,
    const float* __restrict__ sbg_sum, float* __restrict__ out)
{
    __shared__ float red[4];
    const int t = threadIdx.x;
    const float invN = 1.f / 12288.f;     // 3*64*64
    float acc = 0.f;
    #pragma unroll
    for (int r = 0; r < 8; ++r) {
        const int qq = t + 256 * r;       // patch 0..2047
        const float ss = ssim_sum[3*qq] + ssim_sum[3*qq+1] + ssim_sum[3*qq+2];
        const float sa = sa_sum[3*qq]   + sa_sum[3*qq+1]   + sa_sum[3*qq+2];
        const float sb = sbg_sum[3*qq]  + sbg_sum[3*qq+1]  + sbg_sum[3*qq+2];
        const float ssim = ss * invN;
        const float diff = fminf(1.f - ssim, 1.f);     // LD = 1.0
        acc += diff * (sb * invN) + (1.f - diff) * (sa * invN);
    }
    #pragma unroll
    for (int off = 32; off; off >>= 1) acc += __shfl_down(acc, off, 64);
    if ((t & 63) == 0) red[t >> 6] = acc;
    __syncthreads();
    if (t == 0) out[0] = red[0] + red[1] + red[2] + red[3];
}

extern "C" void kernel_launch(void* const* d_in, const int* in_sizes, int n_in,
                              void* d_out, int out_size, void* d_ws, size_t ws_size,
                              hipStream_t stream) {
    const float* A  = (const float*)d_in[0];
    const float* Nn = (const float*)d_in[1];
    const float* GT = (const float*)d_in[2];
    const float* G  = (const float*)d_in[3];
    const float* BG = (const float*)d_in[4];
    float* out      = (float*)d_out;

    float* ssim_sum = (float*)d_ws;            // 6144 floats
    float* sa_sum   = ssim_sum + 6144;         // 6144 floats
    float* sbg_sum  = ssim_sum + 12288;        // 6144 floats

    ssim_fused_kernel<<<dim3(2048, 3), 256, 0, stream>>>(
        A, Nn, GT, G, BG, ssim_sum, sa_sum, sbg_sum);
    combine_kernel<<<1, 256, 0, stream>>>(ssim_sum, sa_sum, sbg_sum, out);
}